// Round 13
// baseline (212.327 us; speedup 1.0000x reference)
//
#include <hip/hip_runtime.h>

typedef unsigned int   u32;
typedef unsigned short u16;
typedef __attribute__((ext_vector_type(8))) short bf16x8;
typedef __attribute__((ext_vector_type(4))) float f32x4;

__device__ __forceinline__ u16 f2b(float f) {
    u32 u = __float_as_uint(f);
    u += 0x7FFFu + ((u >> 16) & 1u);   // round-to-nearest-even
    return (u16)(u >> 16);
}
__device__ __forceinline__ float b2f_lo(u32 v) { return __uint_as_float(v << 16); }
__device__ __forceinline__ float b2f_hi(u32 v) { return __uint_as_float(v & 0xFFFF0000u); }
__device__ __forceinline__ u32 pack2(float a, float b) {
    return (u32)f2b(a) | ((u32)f2b(b) << 16);
}

#define BSHIFT 8                      // 256 nodes per bucket
#define BIN_CHUNK 2048                // edges per k_bin block
#define CAP_MAX 6144                  // max padded bucket capacity (24KB LDS stage)

// ---------------- init: zero bcnt + pack W1 (16 frags) + W2 (4 frags) ----------------

__global__ void k_init(const float* __restrict__ W1, const float* __restrict__ W2,
                       bf16x8* __restrict__ Wpack, bf16x8* __restrict__ W2pack,
                       int* __restrict__ bcnt, int NB) {
    int tid = threadIdx.x;
    for (int i = tid; i < NB; i += 256) bcnt[i] = 0;
    if (tid < 64) {
        int lane = tid;
#pragma unroll
        for (int ct = 0; ct < 4; ct++) {
#pragma unroll
            for (int ks = 0; ks < 4; ks++) {
                bf16x8 h;
#pragma unroll
                for (int j = 0; j < 8; j++) {
                    int k = ks * 32 + ((lane >> 4) << 3) + j;
                    int col = ct * 16 + (lane & 15);
                    h[j] = (short)f2b(W1[k * 64 + col]);
                }
                Wpack[(ct * 4 + ks) * 64 + lane] = h;
            }
        }
#pragma unroll
        for (int ct = 0; ct < 2; ct++) {
#pragma unroll
            for (int ks = 0; ks < 2; ks++) {
                bf16x8 h;
#pragma unroll
                for (int j = 0; j < 8; j++) {
                    int k = ks * 32 + ((lane >> 4) << 3) + j;
                    int col = ct * 16 + (lane & 15);
                    h[j] = (short)f2b(W2[k * 32 + col]);
                }
                W2pack[(ct * 2 + ks) * 64 + lane] = h;
            }
        }
    }
}

// ---------------- bucketed edge binning (R8 verbatim) ----------------

__global__ __launch_bounds__(256) void k_bin(const int* __restrict__ src,
                                             const int* __restrict__ dst,
                                             int* __restrict__ bcnt,
                                             u32* __restrict__ binned,
                                             int E, int NB, int CAP) {
    __shared__ int lh[512], ls[512], gb[512], sh[256];
    __shared__ u32 stage[BIN_CHUNK];
    __shared__ u16 sbuck[BIN_CHUNK];
    int tid = threadIdx.x;
    int base = blockIdx.x * BIN_CHUNK;
    int cnt = E - base;
    if (cnt > BIN_CHUNK) cnt = BIN_CHUNK;

    for (int i = tid; i < 512; i += 256) lh[i] = 0;
    __syncthreads();

    const int T = BIN_CHUNK / 256;
    int bk[T], r[T];
    u32 key[T];
#pragma unroll
    for (int t = 0; t < T; t++) {
        int i = base + t * 256 + tid;
        bk[t] = -1;
        if (i < E) {
            int dv = dst[i];
            bk[t] = dv >> BSHIFT;
            key[t] = ((u32)(dv & 255) << 24) | (u32)src[i];
            r[t] = atomicAdd(&lh[bk[t]], 1);
        }
    }
    __syncthreads();
    {
        int a0 = lh[2 * tid], a1 = lh[2 * tid + 1];
        int sum2 = a0 + a1;
        sh[tid] = sum2;
        __syncthreads();
        for (int dd = 1; dd < 256; dd <<= 1) {
            int x = tid >= dd ? sh[tid - dd] : 0;
            __syncthreads();
            sh[tid] += x;
            __syncthreads();
        }
        int excl = sh[tid] - sum2;
        ls[2 * tid] = excl;
        ls[2 * tid + 1] = excl + a0;
    }
    for (int b = tid; b < NB; b += 256) {
        int c = lh[b];
        gb[b] = c ? atomicAdd(&bcnt[b], c) : 0;
    }
    __syncthreads();
#pragma unroll
    for (int t = 0; t < T; t++) {
        if (bk[t] >= 0) {
            int slot = ls[bk[t]] + r[t];
            stage[slot] = key[t];
            sbuck[slot] = (u16)bk[t];
        }
    }
    __syncthreads();
    for (int j = tid; j < cnt; j += 256) {
        u32 e = stage[j];
        int b = sbuck[j];
        int p = gb[b] + (j - ls[b]);
        if (p < CAP) binned[(size_t)b * CAP + p] = e;
    }
}

// ---------------- fused CSR + gemm1 (R10 verbatim: chunk-major h1b [4][n][16]) ----------------

__global__ __launch_bounds__(256) void k_csr_gemm1(const u32* __restrict__ binned,
                                                   const int* __restrict__ bcnt,
                                                   const bf16x8* __restrict__ Wpack,
                                                   const float* __restrict__ x,
                                                   float* __restrict__ dinv,
                                                   int2* __restrict__ offse,
                                                   int* __restrict__ esrc,
                                                   u16* __restrict__ h1b,
                                                   int n, int CAP) {
    __shared__ u32 stagec[CAP_MAX];
    __shared__ int lcnt[256], lcur[256], sh[256];
    __shared__ float dinv_sh[256];
    int tid = threadIdx.x;
    int b = blockIdx.x;
    size_t base = (size_t)b * CAP;
    int nodeBase = b << BSHIFT;
    int ecnt = bcnt[b];
    if (ecnt > CAP) ecnt = CAP;
    lcnt[tid] = 0;
    __syncthreads();
    for (int j = tid; j < ecnt; j += 256) {
        u32 e = binned[base + j];
        stagec[j] = e;
        atomicAdd(&lcnt[e >> 24], 1);
    }
    __syncthreads();
    int v = lcnt[tid];
    sh[tid] = v;
    __syncthreads();
    for (int d = 1; d < 256; d <<= 1) {
        int xx = tid >= d ? sh[tid - d] : 0;
        __syncthreads();
        sh[tid] += xx;
        __syncthreads();
    }
    int excl = sh[tid] - v;
    int node = nodeBase + tid;
    float dvt = rsqrtf((float)(v + 1));
    dinv_sh[tid] = dvt;
    if (node < n) {
        offse[node] = make_int2((int)base + excl, (int)base + excl + v);
        dinv[node] = dvt;
    }
    lcur[tid] = excl;
    __syncthreads();
    for (int j = tid; j < ecnt; j += 256) {
        u32 e = stagec[j];
        int p = atomicAdd(&lcur[e >> 24], 1);
        esrc[base + p] = (int)(e & 0xFFFFFFu);
    }

    // ---- phase 2: gemm1 for this bucket's rows (chunk-major store) ----
    int wv = tid >> 6, lane = tid & 63;
    bf16x8 bfr[16];
#pragma unroll
    for (int f = 0; f < 16; f++) bfr[f] = Wpack[f * 64 + lane];
    size_t cs = (size_t)n * 16;

    for (int t = wv; t < 16; t += 4) {
        int rowBase = nodeBase + t * 16;
        if (rowBase >= n) break;
        f32x4 acc[4];
#pragma unroll
        for (int ct = 0; ct < 4; ct++) acc[ct] = (f32x4){0.f, 0.f, 0.f, 0.f};

        int r0 = rowBase + (lane & 15);
        if (r0 >= n) r0 = n - 1;           // clamp: D row i only uses A row i
        const float* xr = x + (size_t)r0 * 128 + ((lane >> 4) << 3);
#pragma unroll
        for (int ks = 0; ks < 4; ks++) {
            float4 p0 = *(const float4*)(xr + ks * 32);
            float4 p1 = *(const float4*)(xr + ks * 32 + 4);
            bf16x8 a;
            a[0] = (short)f2b(p0.x); a[1] = (short)f2b(p0.y);
            a[2] = (short)f2b(p0.z); a[3] = (short)f2b(p0.w);
            a[4] = (short)f2b(p1.x); a[5] = (short)f2b(p1.y);
            a[6] = (short)f2b(p1.z); a[7] = (short)f2b(p1.w);
#pragma unroll
            for (int ct = 0; ct < 4; ct++)
                acc[ct] = __builtin_amdgcn_mfma_f32_16x16x32_bf16(a, bfr[ct * 4 + ks], acc[ct], 0, 0, 0);
        }
        // C/D layout: col = lane&15, row = (lane>>4)*4 + r  [m89-verified]
        int lrb = t * 16 + ((lane >> 4) << 2);
#pragma unroll
        for (int r = 0; r < 4; r++) {
            int lrow = lrb + r;
            int row = nodeBase + lrow;
            float dv = dinv_sh[lrow];
#pragma unroll
            for (int ct = 0; ct < 4; ct++) {
                float o = acc[ct][r] * dv;
                float onb = __shfl_xor(o, 1);   // neighbor col
                if (!(lane & 1) && row < n) {
                    *(u32*)&h1b[(size_t)ct * cs + (size_t)row * 16 + (lane & 15)] = pack2(o, onb);
                }
            }
        }
    }
}

// ---------------- XCD-pinned chunked gather (layer 1), ONE launch ----------------
// chunk = (blockIdx%8)%4: each XCD touches only its 3.2MB h1b slice -> L2-resident.
// wave per (node,chunk): 8 groups x 8 lanes (u32 = 2ch), 2 slots.

__global__ __launch_bounds__(256) void k_gather1x(const u16* __restrict__ h1b,
                                                  const int2* __restrict__ offse,
                                                  const int* __restrict__ esrc,
                                                  float* __restrict__ agg,
                                                  int n) {
    int q = blockIdx.x >> 3, r = blockIdx.x & 7;
    int chunk = r & 3;
    int widx = q * 2 + (r >> 2);              // 0..511 within chunk
    int warp = threadIdx.x >> 6, lane = threadIdx.x & 63;
    int g = lane >> 3, jj = lane & 7;
    size_t cs = (size_t)n * 16;
    const u16* h1c = h1b + (size_t)chunk * cs;
    float* aggc = agg + (size_t)chunk * cs;
    for (int wid = widx * 4 + warp; wid < n; wid += 2048) {
        int2 ov = offse[wid];
        float a0 = 0.f, a1 = 0.f, a2 = 0.f, a3 = 0.f;
        if (g == 0) {   // self-loop
            u32 v = *(const u32*)&h1c[(size_t)wid * 16 + 2 * jj];
            a0 += b2f_lo(v); a1 += b2f_hi(v);
        }
        int e = ov.x + g;
        for (; e + 8 < ov.y; e += 16) {       // 2 slots per group
            int s0 = esrc[e], s1 = esrc[e + 8];
            u32 v0 = *(const u32*)&h1c[(size_t)s0 * 16 + 2 * jj];
            u32 v1 = *(const u32*)&h1c[(size_t)s1 * 16 + 2 * jj];
            a0 += b2f_lo(v0); a1 += b2f_hi(v0);
            a2 += b2f_lo(v1); a3 += b2f_hi(v1);
        }
        if (e < ov.y) {
            int s = esrc[e];
            u32 v = *(const u32*)&h1c[(size_t)s * 16 + 2 * jj];
            a0 += b2f_lo(v); a1 += b2f_hi(v);
        }
        a0 += a2; a1 += a3;
        a0 += __shfl_xor(a0, 8);  a1 += __shfl_xor(a1, 8);
        a0 += __shfl_xor(a0, 16); a1 += __shfl_xor(a1, 16);
        a0 += __shfl_xor(a0, 32); a1 += __shfl_xor(a1, 32);
        if (g == 0)
            *(float2*)&aggc[(size_t)wid * 16 + 2 * jj] = make_float2(a0, a1);
    }
}

// ---------------- gemm2 via MFMA (R10 verbatim; h2b store CHUNK-MAJOR [2][n][16]) ----------------

__global__ __launch_bounds__(256) void k_gemm2_mfma(const float* __restrict__ agg,
                                                    const float* __restrict__ dinv,
                                                    const float* __restrict__ b1,
                                                    const bf16x8* __restrict__ W2pack,
                                                    u16* __restrict__ h2b,
                                                    int n, int ntiles) {
    int gwave = (int)((blockIdx.x * blockDim.x + threadIdx.x) >> 6);
    int lane = threadIdx.x & 63;
    if (gwave >= ntiles) return;
    int rowBase = gwave * 16;

    bf16x8 bfr[4];
#pragma unroll
    for (int f = 0; f < 4; f++) bfr[f] = W2pack[f * 64 + lane];
    float b1r[16];
#pragma unroll
    for (int ks = 0; ks < 2; ks++)
#pragma unroll
        for (int j = 0; j < 8; j++)
            b1r[ks * 8 + j] = b1[ks * 32 + ((lane >> 4) << 3) + j];

    int r0 = rowBase + (lane & 15);
    if (r0 >= n) r0 = n - 1;
    float dv0 = dinv[r0];
    size_t cs = (size_t)n * 16;

    f32x4 acc[2];
    acc[0] = (f32x4){0.f, 0.f, 0.f, 0.f};
    acc[1] = (f32x4){0.f, 0.f, 0.f, 0.f};
#pragma unroll
    for (int ks = 0; ks < 2; ks++) {
        int c0 = 2 * ks + ((lane >> 4) >> 1);
        int j0 = ((lane >> 4) & 1) << 3;
        const float* ap = agg + (size_t)c0 * cs + (size_t)r0 * 16 + j0;
        float4 p0 = *(const float4*)ap;
        float4 p1 = *(const float4*)(ap + 4);
        float t[8] = {p0.x, p0.y, p0.z, p0.w, p1.x, p1.y, p1.z, p1.w};
        bf16x8 a;
#pragma unroll
        for (int j = 0; j < 8; j++) {
            float av = t[j] * dv0 + b1r[ks * 8 + j];
            a[j] = (short)f2b(av > 0.f ? av : 0.f);
        }
#pragma unroll
        for (int ct = 0; ct < 2; ct++)
            acc[ct] = __builtin_amdgcn_mfma_f32_16x16x32_bf16(a, bfr[ct * 2 + ks], acc[ct], 0, 0, 0);
    }

    int rbase = rowBase + ((lane >> 4) << 2);
#pragma unroll
    for (int r = 0; r < 4; r++) {
        int row = rbase + r;
        float dv = (row < n) ? dinv[row] : 0.f;
#pragma unroll
        for (int ct = 0; ct < 2; ct++) {
            float o = acc[ct][r] * dv;
            float onb = __shfl_xor(o, 1);
            if (!(lane & 1) && row < n) {
                *(u32*)&h2b[(size_t)ct * cs + (size_t)row * 16 + (lane & 15)] = pack2(o, onb);
            }
        }
    }
}

// ---------------- XCD-pinned chunked final aggregation -> out ----------------
// chunk = (blockIdx%8)%2: each XCD touches only its 3.2MB h2b slice.

__global__ __launch_bounds__(256) void k_agg2x(const u16* __restrict__ h2b,
                                               const int2* __restrict__ offse,
                                               const int* __restrict__ esrc,
                                               const float* __restrict__ dinv,
                                               const float* __restrict__ b2,
                                               float* __restrict__ out, int n) {
    int q = blockIdx.x >> 3, r = blockIdx.x & 7;
    int chunk = r & 1;
    int widx = q * 4 + (r >> 1);              // 0..1023 within chunk
    int warp = threadIdx.x >> 6, lane = threadIdx.x & 63;
    int g = lane >> 3, jj = lane & 7;
    size_t cs = (size_t)n * 16;
    const u16* h2c = h2b + (size_t)chunk * cs;
    float2 bb = *(const float2*)&b2[chunk * 16 + 2 * jj];
    for (int wid = widx * 4 + warp; wid < n; wid += 4096) {
        int2 ov = offse[wid];
        float a0 = 0.f, a1 = 0.f, a2 = 0.f, a3 = 0.f;
        if (g == 0) {   // self-loop
            u32 v = *(const u32*)&h2c[(size_t)wid * 16 + 2 * jj];
            a0 += b2f_lo(v); a1 += b2f_hi(v);
        }
        int e = ov.x + g;
        for (; e + 8 < ov.y; e += 16) {
            int s0 = esrc[e], s1 = esrc[e + 8];
            u32 v0 = *(const u32*)&h2c[(size_t)s0 * 16 + 2 * jj];
            u32 v1 = *(const u32*)&h2c[(size_t)s1 * 16 + 2 * jj];
            a0 += b2f_lo(v0); a1 += b2f_hi(v0);
            a2 += b2f_lo(v1); a3 += b2f_hi(v1);
        }
        if (e < ov.y) {
            int s = esrc[e];
            u32 v = *(const u32*)&h2c[(size_t)s * 16 + 2 * jj];
            a0 += b2f_lo(v); a1 += b2f_hi(v);
        }
        a0 += a2; a1 += a3;
        a0 += __shfl_xor(a0, 8);  a1 += __shfl_xor(a1, 8);
        a0 += __shfl_xor(a0, 16); a1 += __shfl_xor(a1, 16);
        a0 += __shfl_xor(a0, 32); a1 += __shfl_xor(a1, 32);
        if (g == 0) {
            float dv = dinv[wid];
            *(float2*)&out[(size_t)wid * 32 + chunk * 16 + 2 * jj] =
                make_float2(a0 * dv + bb.x, a1 * dv + bb.y);
        }
    }
}

// ---------------- launch ----------------

extern "C" void kernel_launch(void* const* d_in, const int* in_sizes, int n_in,
                              void* d_out, int out_size, void* d_ws, size_t ws_size,
                              hipStream_t stream) {
    const float* x  = (const float*)d_in[0];
    const int*   ei = (const int*)d_in[1];
    const float* W1 = (const float*)d_in[2];
    const float* b1 = (const float*)d_in[3];
    const float* W2 = (const float*)d_in[4];
    const float* b2 = (const float*)d_in[5];
    float* out = (float*)d_out;

    const int n = in_sizes[0] / 128;
    const int E = in_sizes[1] / 2;
    const int* src = ei;
    const int* dst = ei + E;
    const int NB = (n + 255) >> BSHIFT;
    int avg = (E + NB - 1) / NB;
    int CAP = avg + avg / 8 + 512;
    if (CAP > CAP_MAX) CAP = CAP_MAX;

    char* ws = (char*)d_ws;
    size_t woff = 0;
    auto carve = [&](size_t bytes) {
        void* p = ws + woff;
        woff += (bytes + 255) & ~(size_t)255;
        return p;
    };
    int*    bcnt   = (int*)carve((size_t)NB * sizeof(int));
    u32*    binned = (u32*)carve((size_t)NB * CAP * sizeof(u32));
    int2*   offse  = (int2*)carve((size_t)n * sizeof(int2));
    float*  dinv   = (float*)carve((size_t)n * sizeof(float));
    int*    esrc   = (int*)carve((size_t)NB * CAP * sizeof(int));
    bf16x8* Wpack  = (bf16x8*)carve(16 * 64 * sizeof(bf16x8));
    bf16x8* W2pack = (bf16x8*)carve(4 * 64 * sizeof(bf16x8));
    u16*    h1b    = (u16*)carve((size_t)n * 64 * sizeof(u16));     // chunk-major [4][n][16]
    float*  agg    = (float*)carve((size_t)n * 64 * sizeof(float)); // chunk-major [4][n][16]
    u16*    h2b    = (u16*)carve((size_t)n * 32 * sizeof(u16));     // chunk-major [2][n][16]

    const int B = 256;

    // init (zero bcnt + pack W1/W2 fragments)
    k_init<<<1, B, 0, stream>>>(W1, W2, Wpack, W2pack, bcnt, NB);

    // bucketed binning
    k_bin<<<(E + BIN_CHUNK - 1) / BIN_CHUNK, B, 0, stream>>>(src, dst, bcnt, binned, E, NB, CAP);

    // fused CSR build + layer-1 MFMA transform (chunk-major bf16 out)
    k_csr_gemm1<<<NB, B, 0, stream>>>(binned, bcnt, Wpack, x, dinv, offse, esrc, h1b, n, CAP);

    // layer-1 aggregation: XCD-pinned chunks, single launch
    k_gather1x<<<2048, B, 0, stream>>>(h1b, offse, esrc, agg, n);

    // relu + layer-2 transform via MFMA (chunk-major bf16 out)
    int ntiles2 = (n + 15) / 16;
    k_gemm2_mfma<<<(ntiles2 + 3) / 4, B, 0, stream>>>(agg, dinv, b1, W2pack, h2b, n, ntiles2);

    // final aggregation: XCD-pinned chunks -> out (fp32)
    k_agg2x<<<2048, B, 0, stream>>>(h2b, offse, esrc, dinv, b2, out, n);
}

// Round 14
// 197.415 us; speedup vs baseline: 1.0755x; 1.0755x over previous
//
#include <hip/hip_runtime.h>

typedef unsigned int   u32;
typedef unsigned short u16;
typedef long long      s64;
typedef __attribute__((ext_vector_type(8))) short bf16x8;
typedef __attribute__((ext_vector_type(4))) float f32x4;

__device__ __forceinline__ u16 f2b(float f) {
    u32 u = __float_as_uint(f);
    u += 0x7FFFu + ((u >> 16) & 1u);   // round-to-nearest-even
    return (u16)(u >> 16);
}
__device__ __forceinline__ float b2f_lo(u32 v) { return __uint_as_float(v << 16); }
__device__ __forceinline__ float b2f_hi(u32 v) { return __uint_as_float(v & 0xFFFF0000u); }
__device__ __forceinline__ u32 pack2(float a, float b) {
    return (u32)f2b(a) | ((u32)f2b(b) << 16);
}

#define BSHIFT 8                      // 256 nodes per bucket
#define BIN_CHUNK 2048                // edges per k_bin block
#define CAP_MAX 6144                  // max padded bucket capacity (24KB LDS stage)

// ---------------- init: zero bucket counters + pack W1 MFMA B-fragments ----------------

__global__ void k_init(const float* __restrict__ W1, bf16x8* __restrict__ Wpack,
                       int* __restrict__ bcnt, int NB) {
    int tid = threadIdx.x;
    for (int i = tid; i < NB; i += 256) bcnt[i] = 0;
    if (tid < 64) {
        int lane = tid;
#pragma unroll
        for (int ct = 0; ct < 4; ct++) {
#pragma unroll
            for (int ks = 0; ks < 4; ks++) {
                bf16x8 h;
#pragma unroll
                for (int j = 0; j < 8; j++) {
                    int k = ks * 32 + ((lane >> 4) << 3) + j;
                    int col = ct * 16 + (lane & 15);
                    h[j] = (short)f2b(W1[k * 64 + col]);
                }
                Wpack[(ct * 4 + ks) * 64 + lane] = h;
            }
        }
    }
}

// ---------------- bucketed edge binning (nontemporal src/dst reads) ----------------

__global__ __launch_bounds__(256) void k_bin(const int* __restrict__ src,
                                             const int* __restrict__ dst,
                                             int* __restrict__ bcnt,
                                             u32* __restrict__ binned,
                                             int E, int NB, int CAP) {
    __shared__ int lh[512], ls[512], gb[512], sh[256];
    __shared__ u32 stage[BIN_CHUNK];
    __shared__ u16 sbuck[BIN_CHUNK];
    int tid = threadIdx.x;
    int base = blockIdx.x * BIN_CHUNK;
    int cnt = E - base;
    if (cnt > BIN_CHUNK) cnt = BIN_CHUNK;

    for (int i = tid; i < 512; i += 256) lh[i] = 0;
    __syncthreads();

    const int T = BIN_CHUNK / 256;
    int bk[T], r[T];
    u32 key[T];
#pragma unroll
    for (int t = 0; t < T; t++) {
        int i = base + t * 256 + tid;
        bk[t] = -1;
        if (i < E) {
            int dv = __builtin_nontemporal_load(&dst[i]);
            int sv = __builtin_nontemporal_load(&src[i]);
            bk[t] = dv >> BSHIFT;
            key[t] = ((u32)(dv & 255) << 24) | (u32)sv;
            r[t] = atomicAdd(&lh[bk[t]], 1);
        }
    }
    __syncthreads();
    {
        int a0 = lh[2 * tid], a1 = lh[2 * tid + 1];
        int sum2 = a0 + a1;
        sh[tid] = sum2;
        __syncthreads();
        for (int dd = 1; dd < 256; dd <<= 1) {
            int x = tid >= dd ? sh[tid - dd] : 0;
            __syncthreads();
            sh[tid] += x;
            __syncthreads();
        }
        int excl = sh[tid] - sum2;
        ls[2 * tid] = excl;
        ls[2 * tid + 1] = excl + a0;
    }
    for (int b = tid; b < NB; b += 256) {
        int c = lh[b];
        gb[b] = c ? atomicAdd(&bcnt[b], c) : 0;
    }
    __syncthreads();
#pragma unroll
    for (int t = 0; t < T; t++) {
        if (bk[t] >= 0) {
            int slot = ls[bk[t]] + r[t];
            stage[slot] = key[t];
            sbuck[slot] = (u16)bk[t];
        }
    }
    __syncthreads();
    for (int j = tid; j < cnt; j += 256) {
        u32 e = stage[j];
        int b = sbuck[j];
        int p = gb[b] + (j - ls[b]);
        if (p < CAP) binned[(size_t)b * CAP + p] = e;
    }
}

// ---------------- fused CSR + gemm1 (nontemporal binned/x reads) ----------------

__global__ __launch_bounds__(256) void k_csr_gemm1(const u32* __restrict__ binned,
                                                   const int* __restrict__ bcnt,
                                                   const bf16x8* __restrict__ Wpack,
                                                   const float* __restrict__ x,
                                                   float* __restrict__ dinv,
                                                   int2* __restrict__ offse,
                                                   int* __restrict__ esrc,
                                                   u16* __restrict__ h1b,
                                                   int n, int CAP) {
    __shared__ u32 stagec[CAP_MAX];
    __shared__ int lcnt[256], lcur[256], sh[256];
    __shared__ float dinv_sh[256];
    int tid = threadIdx.x;
    int b = blockIdx.x;
    size_t base = (size_t)b * CAP;
    int nodeBase = b << BSHIFT;
    int ecnt = bcnt[b];
    if (ecnt > CAP) ecnt = CAP;
    lcnt[tid] = 0;
    __syncthreads();
    for (int j = tid; j < ecnt; j += 256) {
        u32 e = __builtin_nontemporal_load(&binned[base + j]);
        stagec[j] = e;
        atomicAdd(&lcnt[e >> 24], 1);
    }
    __syncthreads();
    int v = lcnt[tid];
    sh[tid] = v;
    __syncthreads();
    for (int d = 1; d < 256; d <<= 1) {
        int xx = tid >= d ? sh[tid - d] : 0;
        __syncthreads();
        sh[tid] += xx;
        __syncthreads();
    }
    int excl = sh[tid] - v;
    int node = nodeBase + tid;
    float dvt = rsqrtf((float)(v + 1));
    dinv_sh[tid] = dvt;
    if (node < n) {
        offse[node] = make_int2((int)base + excl, (int)base + excl + v);
        dinv[node] = dvt;
    }
    lcur[tid] = excl;
    __syncthreads();
    for (int j = tid; j < ecnt; j += 256) {
        u32 e = stagec[j];
        int p = atomicAdd(&lcur[e >> 24], 1);
        esrc[base + p] = (int)(e & 0xFFFFFFu);
    }

    // ---- phase 2: gemm1 for this bucket's rows ----
    int wv = tid >> 6, lane = tid & 63;
    bf16x8 bfr[16];
#pragma unroll
    for (int f = 0; f < 16; f++) bfr[f] = Wpack[f * 64 + lane];

    for (int t = wv; t < 16; t += 4) {
        int rowBase = nodeBase + t * 16;
        if (rowBase >= n) break;
        f32x4 acc[4];
#pragma unroll
        for (int ct = 0; ct < 4; ct++) acc[ct] = (f32x4){0.f, 0.f, 0.f, 0.f};

        int r0 = rowBase + (lane & 15);
        if (r0 >= n) r0 = n - 1;           // clamp: D row i only uses A row i
        const float* xr = x + (size_t)r0 * 128 + ((lane >> 4) << 3);
#pragma unroll
        for (int ks = 0; ks < 4; ks++) {
            f32x4 p0 = __builtin_nontemporal_load((const f32x4*)(xr + ks * 32));
            f32x4 p1 = __builtin_nontemporal_load((const f32x4*)(xr + ks * 32 + 4));
            bf16x8 a;
            a[0] = (short)f2b(p0[0]); a[1] = (short)f2b(p0[1]);
            a[2] = (short)f2b(p0[2]); a[3] = (short)f2b(p0[3]);
            a[4] = (short)f2b(p1[0]); a[5] = (short)f2b(p1[1]);
            a[6] = (short)f2b(p1[2]); a[7] = (short)f2b(p1[3]);
#pragma unroll
            for (int ct = 0; ct < 4; ct++)
                acc[ct] = __builtin_amdgcn_mfma_f32_16x16x32_bf16(a, bfr[ct * 4 + ks], acc[ct], 0, 0, 0);
        }
        // C/D layout: col = lane&15, row = (lane>>4)*4 + r  [m89-verified]
        int lrb = t * 16 + ((lane >> 4) << 2);
#pragma unroll
        for (int r = 0; r < 4; r++) {
            int lrow = lrb + r;
            int row = nodeBase + lrow;
            float dv = dinv_sh[lrow];
#pragma unroll
            for (int ct = 0; ct < 4; ct++) {
                float o = acc[ct][r] * dv;
                float onb = __shfl_xor(o, 1);   // neighbor col
                if (!(lane & 1) && row < n) {
                    *(u32*)&h1b[(size_t)row * 64 + ct * 16 + (lane & 15)] = pack2(o, onb);
                }
            }
        }
    }
}

// ---------------- fused agg1 + relu + gemm2 (R8 2-slot; nt esrc/offse) ----------------

__global__ __launch_bounds__(256) void k_agg1gemm2(const u16* __restrict__ h1b,
                                                   const int2* __restrict__ offse,
                                                   const int* __restrict__ esrc,
                                                   const float* __restrict__ dinv,
                                                   const float* __restrict__ b1,
                                                   const float* __restrict__ W2,
                                                   u16* __restrict__ h2b, int n) {
    __shared__ float aggL[4][64];
    int warp = threadIdx.x >> 6, lane = threadIdx.x & 63;
    int half = lane >> 5, c2 = lane & 31;
    float w2r[32];
#pragma unroll
    for (int kk = 0; kk < 32; kk++) w2r[kk] = W2[(half * 32 + kk) * 32 + c2];
    float2 bb = *(const float2*)&b1[2 * c2];
    int nwaves = (gridDim.x * blockDim.x) >> 6;
    for (int wid = (int)((blockIdx.x * blockDim.x + threadIdx.x) >> 6); wid < n;
         wid += nwaves) {
        s64 ovl = __builtin_nontemporal_load((const s64*)&offse[wid]);
        int e0 = (int)ovl, e1 = (int)(ovl >> 32);
        float a0 = 0.f, a1 = 0.f, a2 = 0.f, a3 = 0.f;
        if (half == 0) {  // self-loop
            u32 v = *(const u32*)&h1b[(size_t)wid * 64 + 2 * c2];
            a0 += b2f_lo(v); a1 += b2f_hi(v);
        }
        int e = e0 + half;
        for (; e + 2 < e1; e += 4) {         // 2 slots per half-wave in flight
            int s0 = __builtin_nontemporal_load(&esrc[e]);
            int s1 = __builtin_nontemporal_load(&esrc[e + 2]);
            u32 v0 = *(const u32*)&h1b[(size_t)s0 * 64 + 2 * c2];
            u32 v1 = *(const u32*)&h1b[(size_t)s1 * 64 + 2 * c2];
            a0 += b2f_lo(v0); a1 += b2f_hi(v0);
            a2 += b2f_lo(v1); a3 += b2f_hi(v1);
        }
        if (e < e1) {
            int s = __builtin_nontemporal_load(&esrc[e]);
            u32 v = *(const u32*)&h1b[(size_t)s * 64 + 2 * c2];
            a0 += b2f_lo(v); a1 += b2f_hi(v);
        }
        a0 += a2; a1 += a3;
        a0 += __shfl_xor(a0, 32);
        a1 += __shfl_xor(a1, 32);
        float dv = dinv[wid];
        a0 = a0 * dv + bb.x; a1 = a1 * dv + bb.y;
        a0 = a0 > 0.f ? a0 : 0.f;
        a1 = a1 > 0.f ? a1 : 0.f;
        if (half == 0) *(float2*)&aggL[warp][2 * c2] = make_float2(a0, a1);
        asm volatile("s_waitcnt lgkmcnt(0)" ::: "memory");  // wave-internal sync
        float acc = 0.f;
#pragma unroll
        for (int kk = 0; kk < 32; kk += 4) {
            float4 av = *(const float4*)&aggL[warp][half * 32 + kk];
            acc += av.x * w2r[kk] + av.y * w2r[kk + 1] + av.z * w2r[kk + 2] + av.w * w2r[kk + 3];
        }
        acc += __shfl_xor(acc, 32);
        if (half == 0) h2b[(size_t)wid * 32 + c2] = f2b(acc * dv);
    }
}

// ---------------- final aggregation -> out (R8 2-slot; nt esrc/offse/out) ----------------

__global__ __launch_bounds__(256) void k_agg2(const u16* __restrict__ h2b,
                                              const int2* __restrict__ offse,
                                              const int* __restrict__ esrc,
                                              const float* __restrict__ dinv,
                                              const float* __restrict__ b2,
                                              float* __restrict__ out, int n) {
    int wid = (int)((blockIdx.x * blockDim.x + threadIdx.x) >> 6);
    int lane = threadIdx.x & 63;
    int g = lane >> 4, c2 = lane & 15;
    if (wid >= n) return;
    s64 ovl = __builtin_nontemporal_load((const s64*)&offse[wid]);
    int e0 = (int)ovl, e1 = (int)(ovl >> 32);
    float a0 = 0.f, a1 = 0.f, a2 = 0.f, a3 = 0.f;
    int e = e0 + g;
    for (; e + 4 < e1; e += 8) {             // 2 slots per quarter-wave in flight
        int s0 = __builtin_nontemporal_load(&esrc[e]);
        int s1 = __builtin_nontemporal_load(&esrc[e + 4]);
        u32 v0 = *(const u32*)&h2b[(size_t)s0 * 32 + 2 * c2];
        u32 v1 = *(const u32*)&h2b[(size_t)s1 * 32 + 2 * c2];
        a0 += b2f_lo(v0); a1 += b2f_hi(v0);
        a2 += b2f_lo(v1); a3 += b2f_hi(v1);
    }
    if (e < e1) {
        int s = __builtin_nontemporal_load(&esrc[e]);
        u32 v = *(const u32*)&h2b[(size_t)s * 32 + 2 * c2];
        a0 += b2f_lo(v); a1 += b2f_hi(v);
    }
    a0 += a2; a1 += a3;
    a0 += __shfl_xor(a0, 16); a0 += __shfl_xor(a0, 32);
    a1 += __shfl_xor(a1, 16); a1 += __shfl_xor(a1, 32);
    if (g == 0) {
        u32 v = *(const u32*)&h2b[(size_t)wid * 32 + 2 * c2];   // self-loop
        a0 += b2f_lo(v); a1 += b2f_hi(v);
        float dv = dinv[wid];
        __builtin_nontemporal_store(a0 * dv + b2[2 * c2],     &out[(size_t)wid * 32 + 2 * c2]);
        __builtin_nontemporal_store(a1 * dv + b2[2 * c2 + 1], &out[(size_t)wid * 32 + 2 * c2 + 1]);
    }
}

// ---------------- launch ----------------

extern "C" void kernel_launch(void* const* d_in, const int* in_sizes, int n_in,
                              void* d_out, int out_size, void* d_ws, size_t ws_size,
                              hipStream_t stream) {
    const float* x  = (const float*)d_in[0];
    const int*   ei = (const int*)d_in[1];
    const float* W1 = (const float*)d_in[2];
    const float* b1 = (const float*)d_in[3];
    const float* W2 = (const float*)d_in[4];
    const float* b2 = (const float*)d_in[5];
    float* out = (float*)d_out;

    const int n = in_sizes[0] / 128;
    const int E = in_sizes[1] / 2;
    const int* src = ei;
    const int* dst = ei + E;
    const int NB = (n + 255) >> BSHIFT;
    int avg = (E + NB - 1) / NB;
    int CAP = avg + avg / 8 + 512;
    if (CAP > CAP_MAX) CAP = CAP_MAX;

    char* ws = (char*)d_ws;
    size_t woff = 0;
    auto carve = [&](size_t bytes) {
        void* p = ws + woff;
        woff += (bytes + 255) & ~(size_t)255;
        return p;
    };
    int*    bcnt   = (int*)carve((size_t)NB * sizeof(int));
    u32*    binned = (u32*)carve((size_t)NB * CAP * sizeof(u32));
    int2*   offse  = (int2*)carve((size_t)n * sizeof(int2));
    float*  dinv   = (float*)carve((size_t)n * sizeof(float));
    int*    esrc   = (int*)carve((size_t)NB * CAP * sizeof(int));
    bf16x8* Wpack  = (bf16x8*)carve(16 * 64 * sizeof(bf16x8));
    u16*    h1b    = (u16*)carve((size_t)n * 64 * sizeof(u16));
    u16*    h2b    = (u16*)carve((size_t)n * 32 * sizeof(u16));

    const int B = 256;

    // init (zero bcnt + pack W1 fragments)
    k_init<<<1, B, 0, stream>>>(W1, Wpack, bcnt, NB);

    // bucketed binning
    k_bin<<<(E + BIN_CHUNK - 1) / BIN_CHUNK, B, 0, stream>>>(src, dst, bcnt, binned, E, NB, CAP);

    // fused CSR build + layer-1 MFMA transform (bf16 out)
    k_csr_gemm1<<<NB, B, 0, stream>>>(binned, bcnt, Wpack, x, dinv, offse, esrc, h1b, n, CAP);

    // fused: aggregate layer 1 + relu + layer-2 transform (bf16 out)
    k_agg1gemm2<<<2048, B, 0, stream>>>(h1b, offse, esrc, dinv, b1, W2, h2b, n);

    // final aggregation + bias -> out (fp32)
    k_agg2<<<(n + 3) / 4, B, 0, stream>>>(h2b, offse, esrc, dinv, b2, out, n);
}

// Round 15
// 164.925 us; speedup vs baseline: 1.2874x; 1.1970x over previous
//
#include <hip/hip_runtime.h>

typedef unsigned int   u32;
typedef unsigned short u16;
typedef __attribute__((ext_vector_type(8))) short bf16x8;
typedef __attribute__((ext_vector_type(4))) float f32x4;

__device__ __forceinline__ u16 f2b(float f) {
    u32 u = __float_as_uint(f);
    u += 0x7FFFu + ((u >> 16) & 1u);   // round-to-nearest-even
    return (u16)(u >> 16);
}
__device__ __forceinline__ float b2f_lo(u32 v) { return __uint_as_float(v << 16); }
__device__ __forceinline__ float b2f_hi(u32 v) { return __uint_as_float(v & 0xFFFF0000u); }
__device__ __forceinline__ u32 pack2(float a, float b) {
    return (u32)f2b(a) | ((u32)f2b(b) << 16);
}

#define BSHIFT 8                      // 256 nodes per bucket
#define BIN_CHUNK 2048                // edges per k_bin block
#define CAP_MAX 6144                  // max padded bucket capacity (24KB LDS stage)

// ---------------- init: zero bucket counters + pack W1 MFMA B-fragments ----------------

__global__ void k_init(const float* __restrict__ W1, bf16x8* __restrict__ Wpack,
                       int* __restrict__ bcnt, int NB) {
    int tid = threadIdx.x;
    for (int i = tid; i < NB; i += 256) bcnt[i] = 0;
    if (tid < 64) {
        int lane = tid;
#pragma unroll
        for (int ct = 0; ct < 4; ct++) {
#pragma unroll
            for (int ks = 0; ks < 4; ks++) {
                bf16x8 h;
#pragma unroll
                for (int j = 0; j < 8; j++) {
                    int k = ks * 32 + ((lane >> 4) << 3) + j;
                    int col = ct * 16 + (lane & 15);
                    h[j] = (short)f2b(W1[k * 64 + col]);
                }
                Wpack[(ct * 4 + ks) * 64 + lane] = h;
            }
        }
    }
}

// ---------------- bucketed edge binning ----------------

__global__ __launch_bounds__(256) void k_bin(const int* __restrict__ src,
                                             const int* __restrict__ dst,
                                             int* __restrict__ bcnt,
                                             u32* __restrict__ binned,
                                             int E, int NB, int CAP) {
    __shared__ int lh[512], ls[512], gb[512], sh[256];
    __shared__ u32 stage[BIN_CHUNK];
    __shared__ u16 sbuck[BIN_CHUNK];
    int tid = threadIdx.x;
    int base = blockIdx.x * BIN_CHUNK;
    int cnt = E - base;
    if (cnt > BIN_CHUNK) cnt = BIN_CHUNK;

    for (int i = tid; i < 512; i += 256) lh[i] = 0;
    __syncthreads();

    const int T = BIN_CHUNK / 256;
    int bk[T], r[T];
    u32 key[T];
#pragma unroll
    for (int t = 0; t < T; t++) {
        int i = base + t * 256 + tid;
        bk[t] = -1;
        if (i < E) {
            int dv = dst[i];
            bk[t] = dv >> BSHIFT;
            key[t] = ((u32)(dv & 255) << 24) | (u32)src[i];
            r[t] = atomicAdd(&lh[bk[t]], 1);
        }
    }
    __syncthreads();
    {
        int a0 = lh[2 * tid], a1 = lh[2 * tid + 1];
        int sum2 = a0 + a1;
        sh[tid] = sum2;
        __syncthreads();
        for (int dd = 1; dd < 256; dd <<= 1) {
            int x = tid >= dd ? sh[tid - dd] : 0;
            __syncthreads();
            sh[tid] += x;
            __syncthreads();
        }
        int excl = sh[tid] - sum2;
        ls[2 * tid] = excl;
        ls[2 * tid + 1] = excl + a0;
    }
    for (int b = tid; b < NB; b += 256) {
        int c = lh[b];
        gb[b] = c ? atomicAdd(&bcnt[b], c) : 0;
    }
    __syncthreads();
#pragma unroll
    for (int t = 0; t < T; t++) {
        if (bk[t] >= 0) {
            int slot = ls[bk[t]] + r[t];
            stage[slot] = key[t];
            sbuck[slot] = (u16)bk[t];
        }
    }
    __syncthreads();
    for (int j = tid; j < cnt; j += 256) {
        u32 e = stage[j];
        int b = sbuck[j];
        int p = gb[b] + (j - ls[b]);
        if (p < CAP) binned[(size_t)b * CAP + p] = e;
    }
}

// ---------------- fused CSR + gemm1 ----------------

__global__ __launch_bounds__(256) void k_csr_gemm1(const u32* __restrict__ binned,
                                                   const int* __restrict__ bcnt,
                                                   const bf16x8* __restrict__ Wpack,
                                                   const float* __restrict__ x,
                                                   float* __restrict__ dinv,
                                                   int2* __restrict__ offse,
                                                   int* __restrict__ esrc,
                                                   u16* __restrict__ h1b,
                                                   int n, int CAP) {
    __shared__ u32 stagec[CAP_MAX];
    __shared__ int lcnt[256], lcur[256], sh[256];
    __shared__ float dinv_sh[256];
    int tid = threadIdx.x;
    int b = blockIdx.x;
    size_t base = (size_t)b * CAP;
    int nodeBase = b << BSHIFT;
    int ecnt = bcnt[b];
    if (ecnt > CAP) ecnt = CAP;
    lcnt[tid] = 0;
    __syncthreads();
    for (int j = tid; j < ecnt; j += 256) {
        u32 e = binned[base + j];
        stagec[j] = e;
        atomicAdd(&lcnt[e >> 24], 1);
    }
    __syncthreads();
    int v = lcnt[tid];
    sh[tid] = v;
    __syncthreads();
    for (int d = 1; d < 256; d <<= 1) {
        int xx = tid >= d ? sh[tid - d] : 0;
        __syncthreads();
        sh[tid] += xx;
        __syncthreads();
    }
    int excl = sh[tid] - v;
    int node = nodeBase + tid;
    float dvt = rsqrtf((float)(v + 1));
    dinv_sh[tid] = dvt;
    if (node < n) {
        offse[node] = make_int2((int)base + excl, (int)base + excl + v);
        dinv[node] = dvt;
    }
    lcur[tid] = excl;
    __syncthreads();
    for (int j = tid; j < ecnt; j += 256) {
        u32 e = stagec[j];
        int p = atomicAdd(&lcur[e >> 24], 1);
        esrc[base + p] = (int)(e & 0xFFFFFFu);
    }

    // ---- phase 2: gemm1 for this bucket's rows ----
    int wv = tid >> 6, lane = tid & 63;
    bf16x8 bfr[16];
#pragma unroll
    for (int f = 0; f < 16; f++) bfr[f] = Wpack[f * 64 + lane];

    for (int t = wv; t < 16; t += 4) {
        int rowBase = nodeBase + t * 16;
        if (rowBase >= n) break;
        f32x4 acc[4];
#pragma unroll
        for (int ct = 0; ct < 4; ct++) acc[ct] = (f32x4){0.f, 0.f, 0.f, 0.f};

        int r0 = rowBase + (lane & 15);
        if (r0 >= n) r0 = n - 1;           // clamp: D row i only uses A row i
        const float* xr = x + (size_t)r0 * 128 + ((lane >> 4) << 3);
#pragma unroll
        for (int ks = 0; ks < 4; ks++) {
            float4 p0 = *(const float4*)(xr + ks * 32);
            float4 p1 = *(const float4*)(xr + ks * 32 + 4);
            bf16x8 a;
            a[0] = (short)f2b(p0.x); a[1] = (short)f2b(p0.y);
            a[2] = (short)f2b(p0.z); a[3] = (short)f2b(p0.w);
            a[4] = (short)f2b(p1.x); a[5] = (short)f2b(p1.y);
            a[6] = (short)f2b(p1.z); a[7] = (short)f2b(p1.w);
#pragma unroll
            for (int ct = 0; ct < 4; ct++)
                acc[ct] = __builtin_amdgcn_mfma_f32_16x16x32_bf16(a, bfr[ct * 4 + ks], acc[ct], 0, 0, 0);
        }
        // C/D layout: col = lane&15, row = (lane>>4)*4 + r  [m89-verified]
        int lrb = t * 16 + ((lane >> 4) << 2);
#pragma unroll
        for (int r = 0; r < 4; r++) {
            int lrow = lrb + r;
            int row = nodeBase + lrow;
            float dv = dinv_sh[lrow];
#pragma unroll
            for (int ct = 0; ct < 4; ct++) {
                float o = acc[ct][r] * dv;
                float onb = __shfl_xor(o, 1);   // neighbor col
                if (!(lane & 1) && row < n) {
                    *(u32*)&h1b[(size_t)row * 64 + ct * 16 + (lane & 15)] = pack2(o, onb);
                }
            }
        }
    }
}

// ---------------- fused agg1 + relu + gemm2 (bf16 gathers, 2-slot) ----------------

__global__ __launch_bounds__(256) void k_agg1gemm2(const u16* __restrict__ h1b,
                                                   const int2* __restrict__ offse,
                                                   const int* __restrict__ esrc,
                                                   const float* __restrict__ dinv,
                                                   const float* __restrict__ b1,
                                                   const float* __restrict__ W2,
                                                   u16* __restrict__ h2b, int n) {
    __shared__ float aggL[4][64];
    int warp = threadIdx.x >> 6, lane = threadIdx.x & 63;
    int half = lane >> 5, c2 = lane & 31;
    float w2r[32];
#pragma unroll
    for (int kk = 0; kk < 32; kk++) w2r[kk] = W2[(half * 32 + kk) * 32 + c2];
    float2 bb = *(const float2*)&b1[2 * c2];
    int nwaves = (gridDim.x * blockDim.x) >> 6;
    for (int wid = (int)((blockIdx.x * blockDim.x + threadIdx.x) >> 6); wid < n;
         wid += nwaves) {
        int2 ov = offse[wid];
        int e1 = ov.y;
        float a0 = 0.f, a1 = 0.f, a2 = 0.f, a3 = 0.f;
        if (half == 0) {  // self-loop
            u32 v = *(const u32*)&h1b[(size_t)wid * 64 + 2 * c2];
            a0 += b2f_lo(v); a1 += b2f_hi(v);
        }
        int e = ov.x + half;
        for (; e + 2 < e1; e += 4) {         // 2 slots per half-wave in flight
            int s0 = esrc[e], s1 = esrc[e + 2];
            u32 v0 = *(const u32*)&h1b[(size_t)s0 * 64 + 2 * c2];
            u32 v1 = *(const u32*)&h1b[(size_t)s1 * 64 + 2 * c2];
            a0 += b2f_lo(v0); a1 += b2f_hi(v0);
            a2 += b2f_lo(v1); a3 += b2f_hi(v1);
        }
        if (e < e1) {
            int s = esrc[e];
            u32 v = *(const u32*)&h1b[(size_t)s * 64 + 2 * c2];
            a0 += b2f_lo(v); a1 += b2f_hi(v);
        }
        a0 += a2; a1 += a3;
        a0 += __shfl_xor(a0, 32);
        a1 += __shfl_xor(a1, 32);
        float dv = dinv[wid];
        a0 = a0 * dv + bb.x; a1 = a1 * dv + bb.y;
        a0 = a0 > 0.f ? a0 : 0.f;
        a1 = a1 > 0.f ? a1 : 0.f;
        if (half == 0) *(float2*)&aggL[warp][2 * c2] = make_float2(a0, a1);
        asm volatile("s_waitcnt lgkmcnt(0)" ::: "memory");  // wave-internal sync
        float acc = 0.f;
#pragma unroll
        for (int kk = 0; kk < 32; kk += 4) {
            float4 av = *(const float4*)&aggL[warp][half * 32 + kk];
            acc += av.x * w2r[kk] + av.y * w2r[kk + 1] + av.z * w2r[kk + 2] + av.w * w2r[kk + 3];
        }
        acc += __shfl_xor(acc, 32);
        if (half == 0) h2b[(size_t)wid * 32 + c2] = f2b(acc * dv);
    }
}

// ---------------- final aggregation -> out (bf16 gathers, 2-slot) ----------------

__global__ __launch_bounds__(256) void k_agg2(const u16* __restrict__ h2b,
                                              const int2* __restrict__ offse,
                                              const int* __restrict__ esrc,
                                              const float* __restrict__ dinv,
                                              const float* __restrict__ b2,
                                              float* __restrict__ out, int n) {
    int wid = (int)((blockIdx.x * blockDim.x + threadIdx.x) >> 6);
    int lane = threadIdx.x & 63;
    int g = lane >> 4, c2 = lane & 15;
    if (wid >= n) return;
    int2 ov = offse[wid];
    int e1 = ov.y;
    float a0 = 0.f, a1 = 0.f, a2 = 0.f, a3 = 0.f;
    int e = ov.x + g;
    for (; e + 4 < e1; e += 8) {             // 2 slots per quarter-wave in flight
        int s0 = esrc[e], s1 = esrc[e + 4];
        u32 v0 = *(const u32*)&h2b[(size_t)s0 * 32 + 2 * c2];
        u32 v1 = *(const u32*)&h2b[(size_t)s1 * 32 + 2 * c2];
        a0 += b2f_lo(v0); a1 += b2f_hi(v0);
        a2 += b2f_lo(v1); a3 += b2f_hi(v1);
    }
    if (e < e1) {
        int s = esrc[e];
        u32 v = *(const u32*)&h2b[(size_t)s * 32 + 2 * c2];
        a0 += b2f_lo(v); a1 += b2f_hi(v);
    }
    a0 += a2; a1 += a3;
    a0 += __shfl_xor(a0, 16); a0 += __shfl_xor(a0, 32);
    a1 += __shfl_xor(a1, 16); a1 += __shfl_xor(a1, 32);
    if (g == 0) {
        u32 v = *(const u32*)&h2b[(size_t)wid * 32 + 2 * c2];   // self-loop
        a0 += b2f_lo(v); a1 += b2f_hi(v);
        float dv = dinv[wid];
        float2 o = make_float2(a0 * dv + b2[2 * c2], a1 * dv + b2[2 * c2 + 1]);
        *(float2*)&out[(size_t)wid * 32 + 2 * c2] = o;
    }
}

// ---------------- launch ----------------

extern "C" void kernel_launch(void* const* d_in, const int* in_sizes, int n_in,
                              void* d_out, int out_size, void* d_ws, size_t ws_size,
                              hipStream_t stream) {
    const float* x  = (const float*)d_in[0];
    const int*   ei = (const int*)d_in[1];
    const float* W1 = (const float*)d_in[2];
    const float* b1 = (const float*)d_in[3];
    const float* W2 = (const float*)d_in[4];
    const float* b2 = (const float*)d_in[5];
    float* out = (float*)d_out;

    const int n = in_sizes[0] / 128;
    const int E = in_sizes[1] / 2;
    const int* src = ei;
    const int* dst = ei + E;
    const int NB = (n + 255) >> BSHIFT;
    int avg = (E + NB - 1) / NB;
    int CAP = avg + avg / 8 + 512;
    if (CAP > CAP_MAX) CAP = CAP_MAX;

    char* ws = (char*)d_ws;
    size_t woff = 0;
    auto carve = [&](size_t bytes) {
        void* p = ws + woff;
        woff += (bytes + 255) & ~(size_t)255;
        return p;
    };
    int*    bcnt   = (int*)carve((size_t)NB * sizeof(int));
    u32*    binned = (u32*)carve((size_t)NB * CAP * sizeof(u32));
    int2*   offse  = (int2*)carve((size_t)n * sizeof(int2));
    float*  dinv   = (float*)carve((size_t)n * sizeof(float));
    int*    esrc   = (int*)carve((size_t)NB * CAP * sizeof(int));
    bf16x8* Wpack  = (bf16x8*)carve(16 * 64 * sizeof(bf16x8));
    u16*    h1b    = (u16*)carve((size_t)n * 64 * sizeof(u16));
    u16*    h2b    = (u16*)carve((size_t)n * 32 * sizeof(u16));

    const int B = 256;

    // init (zero bcnt + pack W1 fragments)
    k_init<<<1, B, 0, stream>>>(W1, Wpack, bcnt, NB);

    // bucketed binning
    k_bin<<<(E + BIN_CHUNK - 1) / BIN_CHUNK, B, 0, stream>>>(src, dst, bcnt, binned, E, NB, CAP);

    // fused CSR build + layer-1 MFMA transform (bf16 out)
    k_csr_gemm1<<<NB, B, 0, stream>>>(binned, bcnt, Wpack, x, dinv, offse, esrc, h1b, n, CAP);

    // fused: aggregate layer 1 + relu + layer-2 transform (bf16 out)
    k_agg1gemm2<<<2048, B, 0, stream>>>(h1b, offse, esrc, dinv, b1, W2, h2b, n);

    // final aggregation + bias -> out (fp32)
    k_agg2<<<(n + 3) / 4, B, 0, stream>>>(h2b, offse, esrc, dinv, b2, out, n);
}